// Round 25
// baseline (52.163 us; speedup 1.0000x reference)
//
#include <hip/hip_runtime.h>

#define FLT_BIG 3.402823466e38f

// tie-break matches jax.lax.top_k: higher value wins; equal values -> lower index wins
static __device__ __forceinline__ bool better(float v1, int i1, float v2, int i2) {
  return (v1 > v2) || ((v1 == v2) && (i1 < i2));
}

// XCD-aware bijective swizzle (8 XCDs; grid divisible by 8): consecutive logical
// blocks land on the SAME XCD -> shared kmT[h] / K tiles become L2 hits.
static __device__ __forceinline__ int xcd_swizzle(int nblocks) {
  const int bid = blockIdx.x;
  const int chunk = nblocks >> 3;           // blocks per XCD
  return (bid & 7) * chunk + (bid >> 3);
}

// kmT[h][e][n] = mean_j x[(n*32+j)*256 + h*32+e]  (transposed: ball is the fast axis)
__global__ __launch_bounds__(256) void kmeanT_kernel(const float* __restrict__ x,
                                                     float* __restrict__ kmT) {
  __shared__ float4 part[4][64];
  const int n = blockIdx.x;            // ball
  const int t = threadIdx.x;
  const int w = t >> 6, lane = t & 63;
  const int h = lane >> 3, e4 = lane & 7;

  const float* base = x + n * 32 * 256 + h * 32 + e4 * 4;
  float4 a = make_float4(0.f, 0.f, 0.f, 0.f);
  #pragma unroll
  for (int j = 0; j < 8; ++j) {
    const float4 v = *(const float4*)(base + (w * 8 + j) * 256);
    a.x += v.x; a.y += v.y; a.z += v.z; a.w += v.w;
  }
  part[w][lane] = a;
  __syncthreads();

  if (t < 64) {
    float4 s = part[0][t];
    #pragma unroll
    for (int k = 1; k < 4; ++k) {
      const float4 v = part[k][t];
      s.x += v.x; s.y += v.y; s.z += v.z; s.w += v.w;
    }
    const int hh = t >> 3, ee = (t & 7) * 4;
    kmT[hh * 8192 + (ee + 0) * 256 + n] = s.x * (1.0f / 32.0f);
    kmT[hh * 8192 + (ee + 1) * 256 + n] = s.y * (1.0f / 32.0f);
    kmT[hh * 8192 + (ee + 2) * 256 + n] = s.z * (1.0f / 32.0f);
    kmT[hh * 8192 + (ee + 3) * 256 + n] = s.w * (1.0f / 32.0f);
  }
}

// Fused select+attn, block = (h, 32 queries) = one ball. Barrier-free (r23).
// P4 v3: two queries per wave (r24, +10%) with STREAMED K rows — since p_i =
// exp(d_i*s) needs only row i's own dot (no max subtraction), each k row dies
// right after its PV accumulate. Short register lifetimes let the compiler
// overlap row i+1's loads with row i's shfl/exp tail, and make unroll-2 on the
// pair loop feasible (r20's null: the batched kA[8]/kB[8] lifetime blocked it).
// Accumulation order is bit-identical to r24.
__global__ __launch_bounds__(256) void fused_kernel(const float* __restrict__ x,
                                                    const float* __restrict__ kmT,
                                                    float* __restrict__ out) {
  __shared__ float qtile[32 * 32];      // 4 KB, persistent through P4 (wave-local rows)
  __shared__ float simbuf[32 * 260];    // 33.3 KB (wave-local rows)
  const int vb = xcd_swizzle(2048);     // 2048 blocks = 8 heads x 256 q-groups
  const int h = vb >> 8;
  const int qg = vb & 255;
  const int t = threadIdx.x;
  const int w = t >> 6, lane = t & 63;

  // ---- stage the wave's 8 q-rows (coalesced, 8 lanes/row; rows t>>3 wave-local) ----
  {
    const int r = t >> 3, c = t & 7;
    *(float4*)&qtile[r * 32 + c * 4] =
        *(const float4*)(x + (qg * 32 + r) * 256 + h * 32 + c * 4);
  }

  // ---- P1: GEMM acc[qq][j] = q[w*8+qq] . km[4*lane+j] ----
  const float4* kmp = (const float4*)(kmT + h * 8192);   // [32 e][64 float4 over balls]
  float acc[8][4];
  #pragma unroll
  for (int qq = 0; qq < 8; ++qq)
    #pragma unroll
    for (int j = 0; j < 4; ++j) acc[qq][j] = 0.f;

  {
    float4 ka[4], kb[4];
    #pragma unroll
    for (int d = 0; d < 4; ++d) ka[d] = kmp[d * 64 + lane];

    #pragma unroll
    for (int e0 = 0; e0 < 8; ++e0) {               // e0 constant per unrolled iter
      float4* cur = (e0 & 1) ? kb : ka;
      float4* nxt = (e0 & 1) ? ka : kb;
      if (e0 < 7) {
        #pragma unroll
        for (int d = 0; d < 4; ++d) nxt[d] = kmp[((e0 + 1) * 4 + d) * 64 + lane];
      }
      #pragma unroll
      for (int qq = 0; qq < 8; ++qq) {
        const float4 qf = *(const float4*)&qtile[(w * 8 + qq) * 32 + e0 * 4];  // uniform
        acc[qq][0] = fmaf(qf.w, cur[3].x, fmaf(qf.z, cur[2].x, fmaf(qf.y, cur[1].x, fmaf(qf.x, cur[0].x, acc[qq][0]))));
        acc[qq][1] = fmaf(qf.w, cur[3].y, fmaf(qf.z, cur[2].y, fmaf(qf.y, cur[1].y, fmaf(qf.x, cur[0].y, acc[qq][1]))));
        acc[qq][2] = fmaf(qf.w, cur[3].z, fmaf(qf.z, cur[2].z, fmaf(qf.y, cur[1].z, fmaf(qf.x, cur[0].z, acc[qq][2]))));
        acc[qq][3] = fmaf(qf.w, cur[3].w, fmaf(qf.z, cur[2].w, fmaf(qf.y, cur[1].w, fmaf(qf.x, cur[0].w, acc[qq][3]))));
      }
    }
  }

  // ---- P2: sim tile -> simbuf rows w*8..w*8+7 (wave-local); acc dies here ----
  #pragma unroll
  for (int qq = 0; qq < 8; ++qq) {
    *(float4*)&simbuf[(w * 8 + qq) * 260 + lane * 4] =
        make_float4(acc[qq][0], acc[qq][1], acc[qq][2], acc[qq][3]);
  }

  // ---- P3: top-2 scan (thread = (qloc = t>>3, ch = t&7), 32 values) + merge ----
  int pk;
  {
    const int qloc = t >> 3, ch = t & 7;
    const float* rowp = &simbuf[qloc * 260 + ch * 32];
    float a1 = -FLT_BIG, a2 = -FLT_BIG;
    int j1 = 0, j2 = 0;
    #pragma unroll
    for (int i = 0; i < 8; ++i) {
      const float4 v4 = *(const float4*)(rowp + i * 4);
      const int b0 = ch * 32 + i * 4;
      // ascending-index scan: strict > is tie-exact (later index loses ties)
      if (v4.x > a1) { a2 = a1; j2 = j1; a1 = v4.x; j1 = b0; }
      else if (v4.x > a2) { a2 = v4.x; j2 = b0; }
      if (v4.y > a1) { a2 = a1; j2 = j1; a1 = v4.y; j1 = b0 + 1; }
      else if (v4.y > a2) { a2 = v4.y; j2 = b0 + 1; }
      if (v4.z > a1) { a2 = a1; j2 = j1; a1 = v4.z; j1 = b0 + 2; }
      else if (v4.z > a2) { a2 = v4.z; j2 = b0 + 2; }
      if (v4.w > a1) { a2 = a1; j2 = j1; a1 = v4.w; j1 = b0 + 3; }
      else if (v4.w > a2) { a2 = v4.w; j2 = b0 + 3; }
    }

    pk = j1 | (j2 << 16);
    #pragma unroll
    for (int m = 1; m <= 4; m <<= 1) {
      const float b1 = __shfl_xor(a1, m);
      const float b2 = __shfl_xor(a2, m);
      const int bpk = __shfl_xor(pk, m);
      const int bj1 = bpk & 65535, bj2 = bpk >> 16;
      int c1 = pk & 65535, c2 = pk >> 16;
      if (better(b1, bj1, a1, c1)) {
        if (better(a1, c1, b2, bj2)) { a2 = a1; c2 = c1; } else { a2 = b2; c2 = bj2; }
        a1 = b1; c1 = bj1;
      } else if (better(b1, bj1, a2, c2)) { a2 = b1; c2 = bj1; }
      pk = c1 | (c2 << 16);
    }
    // pk for local query ql lives (replicated) in lanes ql*8 + 0..7
  }

  // ---- P4 v3: two queries in flight (32-lane half each), K rows streamed ----
  const int o = lane & 7;              // 16B chunk within row
  const int qp = lane >> 5;            // which query of the pair this half owns
  const int ro4 = (lane >> 3) & 3;     // row group within the half
  #pragma unroll 2
  for (int pair = 0; pair < 4; ++pair) {
    const int ql = pair * 2 + qp;              // local query 0..7 (per half)
    const int qloc = w * 8 + ql;
    const int pkq = __shfl(pk, ql * 8);        // broadcast query ql's top-2
    const int bA = pkq & 65535, bB = pkq >> 16;
    const float4 qf = *(const float4*)&qtile[qloc * 32 + o * 4];

    const float* xa = x + bA * 8192 + ro4 * 256 + h * 32 + o * 4;
    const float* xb = x + bB * 8192 + ro4 * 256 + h * 32 + o * 4;

    float psum = 0.f, ox = 0.f, oy = 0.f, oz = 0.f, ow = 0.f;
    #pragma unroll
    for (int i = 0; i < 8; ++i) {              // rows ro4 + 4i; k dies per iteration
      const float4 ka = *(const float4*)(xa + i * 1024);
      const float4 kb = *(const float4*)(xb + i * 1024);

      float a = qf.x * ka.x; a = fmaf(qf.y, ka.y, a);
      a = fmaf(qf.z, ka.z, a); a = fmaf(qf.w, ka.w, a);
      float b = qf.x * kb.x; b = fmaf(qf.y, kb.y, b);
      b = fmaf(qf.z, kb.z, b); b = fmaf(qf.w, kb.w, b);
      // finish this row's dot across the 8 o-lanes (xor 1/2/4 within the half)
      a += __shfl_xor(a, 1); a += __shfl_xor(a, 2); a += __shfl_xor(a, 4);
      b += __shfl_xor(b, 1); b += __shfl_xor(b, 2); b += __shfl_xor(b, 4);

      const float pa = __expf(a * 0.0625f);
      const float pb = __expf(b * 0.0625f);
      psum += pa + pb;

      ox = fmaf(pa, ka.x, ox); oy = fmaf(pa, ka.y, oy);
      oz = fmaf(pa, ka.z, oz); ow = fmaf(pa, ka.w, ow);
      ox = fmaf(pb, kb.x, ox); oy = fmaf(pb, kb.y, oy);
      oz = fmaf(pb, kb.z, oz); ow = fmaf(pb, kb.w, ow);
    }

    // reduce over the ro4 lanes (xor 8/16, stays within the 32-lane half)
    #pragma unroll
    for (int m = 8; m <= 16; m <<= 1) {
      psum += __shfl_xor(psum, m);
      ox += __shfl_xor(ox, m);
      oy += __shfl_xor(oy, m);
      oz += __shfl_xor(oz, m);
      ow += __shfl_xor(ow, m);
    }

    const float inv = 1.0f / psum;
    if (ro4 == 0) {
      *(float4*)(out + (qg * 32 + qloc) * 256 + h * 32 + o * 4) =
          make_float4(ox * inv, oy * inv, oz * inv, ow * inv);
    }
  }
}

extern "C" void kernel_launch(void* const* d_in, const int* in_sizes, int n_in,
                              void* d_out, int out_size, void* d_ws, size_t ws_size,
                              hipStream_t stream) {
  const float* x = (const float*)d_in[0];   // (8192, 256) fp32; pos (d_in[1]) is dead code
  float* kmT = (float*)d_ws;                // 256 KB
  float* out = (float*)d_out;

  kmeanT_kernel<<<256, 256, 0, stream>>>(x, kmT);
  fused_kernel<<<2048, 256, 0, stream>>>(x, kmT, out);
}

// Round 26
// 49.281 us; speedup vs baseline: 1.0585x; 1.0585x over previous
//
#include <hip/hip_runtime.h>

#define FLT_BIG 3.402823466e38f

// tie-break matches jax.lax.top_k: higher value wins; equal values -> lower index wins
static __device__ __forceinline__ bool better(float v1, int i1, float v2, int i2) {
  return (v1 > v2) || ((v1 == v2) && (i1 < i2));
}

// XCD-aware bijective swizzle (8 XCDs; grid divisible by 8): consecutive logical
// blocks land on the SAME XCD -> shared kmT[h] / K tiles become L2 hits.
static __device__ __forceinline__ int xcd_swizzle(int nblocks) {
  const int bid = blockIdx.x;
  const int chunk = nblocks >> 3;           // blocks per XCD
  return (bid & 7) * chunk + (bid >> 3);
}

// kmT[h][e][n] = mean_j x[(n*32+j)*256 + h*32+e]  (transposed: ball is the fast axis)
__global__ __launch_bounds__(256) void kmeanT_kernel(const float* __restrict__ x,
                                                     float* __restrict__ kmT) {
  __shared__ float4 part[4][64];
  const int n = blockIdx.x;            // ball
  const int t = threadIdx.x;
  const int w = t >> 6, lane = t & 63;
  const int h = lane >> 3, e4 = lane & 7;

  const float* base = x + n * 32 * 256 + h * 32 + e4 * 4;
  float4 a = make_float4(0.f, 0.f, 0.f, 0.f);
  #pragma unroll
  for (int j = 0; j < 8; ++j) {
    const float4 v = *(const float4*)(base + (w * 8 + j) * 256);
    a.x += v.x; a.y += v.y; a.z += v.z; a.w += v.w;
  }
  part[w][lane] = a;
  __syncthreads();

  if (t < 64) {
    float4 s = part[0][t];
    #pragma unroll
    for (int k = 1; k < 4; ++k) {
      const float4 v = part[k][t];
      s.x += v.x; s.y += v.y; s.z += v.z; s.w += v.w;
    }
    const int hh = t >> 3, ee = (t & 7) * 4;
    kmT[hh * 8192 + (ee + 0) * 256 + n] = s.x * (1.0f / 32.0f);
    kmT[hh * 8192 + (ee + 1) * 256 + n] = s.y * (1.0f / 32.0f);
    kmT[hh * 8192 + (ee + 2) * 256 + n] = s.z * (1.0f / 32.0f);
    kmT[hh * 8192 + (ee + 3) * 256 + n] = s.w * (1.0f / 32.0f);
  }
}

// Fused select+attn, block = (h, 32 queries) = one ball. Barrier-free (r23).
// P4 v4: EIGHT queries per wave — one 8-lane group per query (r24 proved the
// width lever: 2 q/wave = +10%). Three wins fall out of the layout:
//  - P3's pk for query t>>3 is already replicated across that thread's 8
//    ch-lanes = exactly P4's group -> no broadcast shfl at all;
//  - after the dot's xor-1/2/4 group reduce, p is replicated group-wide, so
//    psum and the PV accumulator are lane-local: ZERO final reduce stages
//    (r24 had 2 stages x 5 values per pair);
//  - all 32 K rows stream through one unrolled loop (max ILP), every lane
//    writes its own output chunk (no idle (ro!=0) lanes).
// Mask provably all-true (topv2 >> 1e-10); softmax without max shift (|logit|<~5).
__global__ __launch_bounds__(256) void fused_kernel(const float* __restrict__ x,
                                                    const float* __restrict__ kmT,
                                                    float* __restrict__ out) {
  __shared__ float qtile[32 * 32];      // 4 KB, persistent through P4 (wave-local rows)
  __shared__ float simbuf[32 * 260];    // 33.3 KB (wave-local rows)
  const int vb = xcd_swizzle(2048);     // 2048 blocks = 8 heads x 256 q-groups
  const int h = vb >> 8;
  const int qg = vb & 255;
  const int t = threadIdx.x;
  const int w = t >> 6, lane = t & 63;

  // ---- stage the wave's 8 q-rows (coalesced, 8 lanes/row; rows t>>3 wave-local) ----
  {
    const int r = t >> 3, c = t & 7;
    *(float4*)&qtile[r * 32 + c * 4] =
        *(const float4*)(x + (qg * 32 + r) * 256 + h * 32 + c * 4);
  }

  // ---- P1: GEMM acc[qq][j] = q[w*8+qq] . km[4*lane+j] ----
  const float4* kmp = (const float4*)(kmT + h * 8192);   // [32 e][64 float4 over balls]
  float acc[8][4];
  #pragma unroll
  for (int qq = 0; qq < 8; ++qq)
    #pragma unroll
    for (int j = 0; j < 4; ++j) acc[qq][j] = 0.f;

  {
    float4 ka[4], kb[4];
    #pragma unroll
    for (int d = 0; d < 4; ++d) ka[d] = kmp[d * 64 + lane];

    #pragma unroll
    for (int e0 = 0; e0 < 8; ++e0) {               // e0 constant per unrolled iter
      float4* cur = (e0 & 1) ? kb : ka;
      float4* nxt = (e0 & 1) ? ka : kb;
      if (e0 < 7) {
        #pragma unroll
        for (int d = 0; d < 4; ++d) nxt[d] = kmp[((e0 + 1) * 4 + d) * 64 + lane];
      }
      #pragma unroll
      for (int qq = 0; qq < 8; ++qq) {
        const float4 qf = *(const float4*)&qtile[(w * 8 + qq) * 32 + e0 * 4];  // uniform
        acc[qq][0] = fmaf(qf.w, cur[3].x, fmaf(qf.z, cur[2].x, fmaf(qf.y, cur[1].x, fmaf(qf.x, cur[0].x, acc[qq][0]))));
        acc[qq][1] = fmaf(qf.w, cur[3].y, fmaf(qf.z, cur[2].y, fmaf(qf.y, cur[1].y, fmaf(qf.x, cur[0].y, acc[qq][1]))));
        acc[qq][2] = fmaf(qf.w, cur[3].z, fmaf(qf.z, cur[2].z, fmaf(qf.y, cur[1].z, fmaf(qf.x, cur[0].z, acc[qq][2]))));
        acc[qq][3] = fmaf(qf.w, cur[3].w, fmaf(qf.z, cur[2].w, fmaf(qf.y, cur[1].w, fmaf(qf.x, cur[0].w, acc[qq][3]))));
      }
    }
  }

  // ---- P2: sim tile -> simbuf rows w*8..w*8+7 (wave-local); acc dies here ----
  #pragma unroll
  for (int qq = 0; qq < 8; ++qq) {
    *(float4*)&simbuf[(w * 8 + qq) * 260 + lane * 4] =
        make_float4(acc[qq][0], acc[qq][1], acc[qq][2], acc[qq][3]);
  }

  // ---- P3: top-2 scan (thread = (qloc = t>>3, ch = t&7), 32 values) + merge ----
  int pk;
  {
    const int qloc = t >> 3, ch = t & 7;
    const float* rowp = &simbuf[qloc * 260 + ch * 32];
    float a1 = -FLT_BIG, a2 = -FLT_BIG;
    int j1 = 0, j2 = 0;
    #pragma unroll
    for (int i = 0; i < 8; ++i) {
      const float4 v4 = *(const float4*)(rowp + i * 4);
      const int b0 = ch * 32 + i * 4;
      // ascending-index scan: strict > is tie-exact (later index loses ties)
      if (v4.x > a1) { a2 = a1; j2 = j1; a1 = v4.x; j1 = b0; }
      else if (v4.x > a2) { a2 = v4.x; j2 = b0; }
      if (v4.y > a1) { a2 = a1; j2 = j1; a1 = v4.y; j1 = b0 + 1; }
      else if (v4.y > a2) { a2 = v4.y; j2 = b0 + 1; }
      if (v4.z > a1) { a2 = a1; j2 = j1; a1 = v4.z; j1 = b0 + 2; }
      else if (v4.z > a2) { a2 = v4.z; j2 = b0 + 2; }
      if (v4.w > a1) { a2 = a1; j2 = j1; a1 = v4.w; j1 = b0 + 3; }
      else if (v4.w > a2) { a2 = v4.w; j2 = b0 + 3; }
    }

    pk = j1 | (j2 << 16);
    #pragma unroll
    for (int m = 1; m <= 4; m <<= 1) {
      const float b1 = __shfl_xor(a1, m);
      const float b2 = __shfl_xor(a2, m);
      const int bpk = __shfl_xor(pk, m);
      const int bj1 = bpk & 65535, bj2 = bpk >> 16;
      int c1 = pk & 65535, c2 = pk >> 16;
      if (better(b1, bj1, a1, c1)) {
        if (better(a1, c1, b2, bj2)) { a2 = a1; c2 = c1; } else { a2 = b2; c2 = bj2; }
        a1 = b1; c1 = bj1;
      } else if (better(b1, bj1, a2, c2)) { a2 = b1; c2 = bj1; }
      pk = c1 | (c2 << 16);
    }
    // pk for query t>>3 is now replicated across this thread's 8 ch-lanes —
    // exactly P4's 8-lane group: no further broadcast needed.
  }

  // ---- P4 v4: 8 queries concurrently; 8-lane group (o = lane&7) per query ----
  const int o = lane & 7;
  const int ql = lane >> 3;            // group = local query 0..7
  const int qloc = w * 8 + ql;
  const int bA = pk & 65535, bB = pk >> 16;
  const float4 qf = *(const float4*)&qtile[qloc * 32 + o * 4];

  const float* xa = x + bA * 8192 + h * 32 + o * 4;
  const float* xb = x + bB * 8192 + h * 32 + o * 4;

  float psum = 0.f, ox = 0.f, oy = 0.f, oz = 0.f, ow = 0.f;
  #pragma unroll
  for (int i = 0; i < 32; ++i) {       // all 32 rows streamed; k dies per iteration
    const float4 ka = *(const float4*)(xa + i * 256);
    const float4 kb = *(const float4*)(xb + i * 256);

    float a = qf.x * ka.x; a = fmaf(qf.y, ka.y, a);
    a = fmaf(qf.z, ka.z, a); a = fmaf(qf.w, ka.w, a);
    float b = qf.x * kb.x; b = fmaf(qf.y, kb.y, b);
    b = fmaf(qf.z, kb.z, b); b = fmaf(qf.w, kb.w, b);
    // finish this row's dot across the 8 o-lanes (group-internal xor 1/2/4)
    a += __shfl_xor(a, 1); a += __shfl_xor(a, 2); a += __shfl_xor(a, 4);
    b += __shfl_xor(b, 1); b += __shfl_xor(b, 2); b += __shfl_xor(b, 4);

    const float pa = __expf(a * 0.0625f);
    const float pb = __expf(b * 0.0625f);
    psum += pa + pb;                   // replicated group-wide: lane-local from here

    ox = fmaf(pa, ka.x, ox); oy = fmaf(pa, ka.y, oy);
    oz = fmaf(pa, ka.z, oz); ow = fmaf(pa, ka.w, ow);
    ox = fmaf(pb, kb.x, ox); oy = fmaf(pb, kb.y, oy);
    oz = fmaf(pb, kb.z, oz); ow = fmaf(pb, kb.w, ow);
  }

  // no cross-lane reduce: psum and (ox..ow) are complete per lane
  const float inv = 1.0f / psum;
  *(float4*)(out + (qg * 32 + qloc) * 256 + h * 32 + o * 4) =
      make_float4(ox * inv, oy * inv, oz * inv, ow * inv);
}

extern "C" void kernel_launch(void* const* d_in, const int* in_sizes, int n_in,
                              void* d_out, int out_size, void* d_ws, size_t ws_size,
                              hipStream_t stream) {
  const float* x = (const float*)d_in[0];   // (8192, 256) fp32; pos (d_in[1]) is dead code
  float* kmT = (float*)d_ws;                // 256 KB
  float* out = (float*)d_out;

  kmeanT_kernel<<<256, 256, 0, stream>>>(x, kmT);
  fused_kernel<<<2048, 256, 0, stream>>>(x, kmT, out);
}

// Round 27
// 48.820 us; speedup vs baseline: 1.0685x; 1.0094x over previous
//
#include <hip/hip_runtime.h>

#define FLT_BIG 3.402823466e38f

// tie-break matches jax.lax.top_k: higher value wins; equal values -> lower index wins
static __device__ __forceinline__ bool better(float v1, int i1, float v2, int i2) {
  return (v1 > v2) || ((v1 == v2) && (i1 < i2));
}

// XCD-aware bijective swizzle (8 XCDs; grid divisible by 8): consecutive logical
// blocks land on the SAME XCD -> shared kmT[h] / K tiles become L2 hits.
static __device__ __forceinline__ int xcd_swizzle(int nblocks) {
  const int bid = blockIdx.x;
  const int chunk = nblocks >> 3;           // blocks per XCD
  return (bid & 7) * chunk + (bid >> 3);
}

// kmT[h][e][n] = mean_j x[(n*32+j)*256 + h*32+e]  (transposed: ball is the fast axis)
__global__ __launch_bounds__(256) void kmeanT_kernel(const float* __restrict__ x,
                                                     float* __restrict__ kmT) {
  __shared__ float4 part[4][64];
  const int n = blockIdx.x;            // ball
  const int t = threadIdx.x;
  const int w = t >> 6, lane = t & 63;
  const int h = lane >> 3, e4 = lane & 7;

  const float* base = x + n * 32 * 256 + h * 32 + e4 * 4;
  float4 a = make_float4(0.f, 0.f, 0.f, 0.f);
  #pragma unroll
  for (int j = 0; j < 8; ++j) {
    const float4 v = *(const float4*)(base + (w * 8 + j) * 256);
    a.x += v.x; a.y += v.y; a.z += v.z; a.w += v.w;
  }
  part[w][lane] = a;
  __syncthreads();

  if (t < 64) {
    float4 s = part[0][t];
    #pragma unroll
    for (int k = 1; k < 4; ++k) {
      const float4 v = part[k][t];
      s.x += v.x; s.y += v.y; s.z += v.z; s.w += v.w;
    }
    const int hh = t >> 3, ee = (t & 7) * 4;
    kmT[hh * 8192 + (ee + 0) * 256 + n] = s.x * (1.0f / 32.0f);
    kmT[hh * 8192 + (ee + 1) * 256 + n] = s.y * (1.0f / 32.0f);
    kmT[hh * 8192 + (ee + 2) * 256 + n] = s.z * (1.0f / 32.0f);
    kmT[hh * 8192 + (ee + 3) * 256 + n] = s.w * (1.0f / 32.0f);
  }
}

// Fused select+attn, block = (h, 32 queries) = one ball. Barrier-free (r23).
// P1 v2: depth-2 km prefetch — 3 rotating float4[4] buffers, all indices
// compile-time (rule #20: the e0 loop is fully unrolled, so kbuf[(e0+2)%3]
// is a static index). Depth-1 ping-pong gave ~280 cyc slack vs ~200-300 cyc
// L2 latency (marginal); depth-2 gives ~560. Math bit-identical to r26.
// P4 (r26): 8 queries/wave, one 8-lane group each; streamed K rows; zero
// final reduce stages; lane-local psum/PV.
__global__ __launch_bounds__(256) void fused_kernel(const float* __restrict__ x,
                                                    const float* __restrict__ kmT,
                                                    float* __restrict__ out) {
  __shared__ float qtile[32 * 32];      // 4 KB, persistent through P4 (wave-local rows)
  __shared__ float simbuf[32 * 260];    // 33.3 KB (wave-local rows)
  const int vb = xcd_swizzle(2048);     // 2048 blocks = 8 heads x 256 q-groups
  const int h = vb >> 8;
  const int qg = vb & 255;
  const int t = threadIdx.x;
  const int w = t >> 6, lane = t & 63;

  // ---- stage the wave's 8 q-rows (coalesced, 8 lanes/row; rows t>>3 wave-local) ----
  {
    const int r = t >> 3, c = t & 7;
    *(float4*)&qtile[r * 32 + c * 4] =
        *(const float4*)(x + (qg * 32 + r) * 256 + h * 32 + c * 4);
  }

  // ---- P1 v2: GEMM acc[qq][j] = q[w*8+qq] . km[4*lane+j], depth-2 prefetch ----
  const float4* kmp = (const float4*)(kmT + h * 8192);   // [32 e][64 float4 over balls]
  float acc[8][4];
  #pragma unroll
  for (int qq = 0; qq < 8; ++qq)
    #pragma unroll
    for (int j = 0; j < 4; ++j) acc[qq][j] = 0.f;

  {
    float4 kbuf[3][4];
    #pragma unroll
    for (int d = 0; d < 4; ++d) kbuf[0][d] = kmp[d * 64 + lane];            // e0=0
    #pragma unroll
    for (int d = 0; d < 4; ++d) kbuf[1][d] = kmp[(4 + d) * 64 + lane];      // e0=1

    #pragma unroll
    for (int e0 = 0; e0 < 8; ++e0) {               // fully unrolled: static indices
      const float4* cur = kbuf[e0 % 3];
      if (e0 < 6) {
        float4* nxt = kbuf[(e0 + 2) % 3];
        #pragma unroll
        for (int d = 0; d < 4; ++d) nxt[d] = kmp[((e0 + 2) * 4 + d) * 64 + lane];
      }
      #pragma unroll
      for (int qq = 0; qq < 8; ++qq) {
        const float4 qf = *(const float4*)&qtile[(w * 8 + qq) * 32 + e0 * 4];  // uniform
        acc[qq][0] = fmaf(qf.w, cur[3].x, fmaf(qf.z, cur[2].x, fmaf(qf.y, cur[1].x, fmaf(qf.x, cur[0].x, acc[qq][0]))));
        acc[qq][1] = fmaf(qf.w, cur[3].y, fmaf(qf.z, cur[2].y, fmaf(qf.y, cur[1].y, fmaf(qf.x, cur[0].y, acc[qq][1]))));
        acc[qq][2] = fmaf(qf.w, cur[3].z, fmaf(qf.z, cur[2].z, fmaf(qf.y, cur[1].z, fmaf(qf.x, cur[0].z, acc[qq][2]))));
        acc[qq][3] = fmaf(qf.w, cur[3].w, fmaf(qf.z, cur[2].w, fmaf(qf.y, cur[1].w, fmaf(qf.x, cur[0].w, acc[qq][3]))));
      }
    }
  }

  // ---- P2: sim tile -> simbuf rows w*8..w*8+7 (wave-local); acc dies here ----
  #pragma unroll
  for (int qq = 0; qq < 8; ++qq) {
    *(float4*)&simbuf[(w * 8 + qq) * 260 + lane * 4] =
        make_float4(acc[qq][0], acc[qq][1], acc[qq][2], acc[qq][3]);
  }

  // ---- P3: top-2 scan (thread = (qloc = t>>3, ch = t&7), 32 values) + merge ----
  int pk;
  {
    const int qloc = t >> 3, ch = t & 7;
    const float* rowp = &simbuf[qloc * 260 + ch * 32];
    float a1 = -FLT_BIG, a2 = -FLT_BIG;
    int j1 = 0, j2 = 0;
    #pragma unroll
    for (int i = 0; i < 8; ++i) {
      const float4 v4 = *(const float4*)(rowp + i * 4);
      const int b0 = ch * 32 + i * 4;
      // ascending-index scan: strict > is tie-exact (later index loses ties)
      if (v4.x > a1) { a2 = a1; j2 = j1; a1 = v4.x; j1 = b0; }
      else if (v4.x > a2) { a2 = v4.x; j2 = b0; }
      if (v4.y > a1) { a2 = a1; j2 = j1; a1 = v4.y; j1 = b0 + 1; }
      else if (v4.y > a2) { a2 = v4.y; j2 = b0 + 1; }
      if (v4.z > a1) { a2 = a1; j2 = j1; a1 = v4.z; j1 = b0 + 2; }
      else if (v4.z > a2) { a2 = v4.z; j2 = b0 + 2; }
      if (v4.w > a1) { a2 = a1; j2 = j1; a1 = v4.w; j1 = b0 + 3; }
      else if (v4.w > a2) { a2 = v4.w; j2 = b0 + 3; }
    }

    pk = j1 | (j2 << 16);
    #pragma unroll
    for (int m = 1; m <= 4; m <<= 1) {
      const float b1 = __shfl_xor(a1, m);
      const float b2 = __shfl_xor(a2, m);
      const int bpk = __shfl_xor(pk, m);
      const int bj1 = bpk & 65535, bj2 = bpk >> 16;
      int c1 = pk & 65535, c2 = pk >> 16;
      if (better(b1, bj1, a1, c1)) {
        if (better(a1, c1, b2, bj2)) { a2 = a1; c2 = c1; } else { a2 = b2; c2 = bj2; }
        a1 = b1; c1 = bj1;
      } else if (better(b1, bj1, a2, c2)) { a2 = b1; c2 = bj1; }
      pk = c1 | (c2 << 16);
    }
    // pk for query t>>3 is replicated across this thread's 8 ch-lanes —
    // exactly P4's 8-lane group: no further broadcast needed.
  }

  // ---- P4: 8 queries concurrently; 8-lane group (o = lane&7) per query ----
  const int o = lane & 7;
  const int ql = lane >> 3;            // group = local query 0..7
  const int qloc = w * 8 + ql;
  const int bA = pk & 65535, bB = pk >> 16;
  const float4 qf = *(const float4*)&qtile[qloc * 32 + o * 4];

  const float* xa = x + bA * 8192 + h * 32 + o * 4;
  const float* xb = x + bB * 8192 + h * 32 + o * 4;

  float psum = 0.f, ox = 0.f, oy = 0.f, oz = 0.f, ow = 0.f;
  #pragma unroll
  for (int i = 0; i < 32; ++i) {       // all 32 rows streamed; k dies per iteration
    const float4 ka = *(const float4*)(xa + i * 256);
    const float4 kb = *(const float4*)(xb + i * 256);

    float a = qf.x * ka.x; a = fmaf(qf.y, ka.y, a);
    a = fmaf(qf.z, ka.z, a); a = fmaf(qf.w, ka.w, a);
    float b = qf.x * kb.x; b = fmaf(qf.y, kb.y, b);
    b = fmaf(qf.z, kb.z, b); b = fmaf(qf.w, kb.w, b);
    // finish this row's dot across the 8 o-lanes (group-internal xor 1/2/4)
    a += __shfl_xor(a, 1); a += __shfl_xor(a, 2); a += __shfl_xor(a, 4);
    b += __shfl_xor(b, 1); b += __shfl_xor(b, 2); b += __shfl_xor(b, 4);

    const float pa = __expf(a * 0.0625f);
    const float pb = __expf(b * 0.0625f);
    psum += pa + pb;                   // replicated group-wide: lane-local from here

    ox = fmaf(pa, ka.x, ox); oy = fmaf(pa, ka.y, oy);
    oz = fmaf(pa, ka.z, oz); ow = fmaf(pa, ka.w, ow);
    ox = fmaf(pb, kb.x, ox); oy = fmaf(pb, kb.y, oy);
    oz = fmaf(pb, kb.z, oz); ow = fmaf(pb, kb.w, ow);
  }

  // no cross-lane reduce: psum and (ox..ow) are complete per lane
  const float inv = 1.0f / psum;
  *(float4*)(out + (qg * 32 + qloc) * 256 + h * 32 + o * 4) =
      make_float4(ox * inv, oy * inv, oz * inv, ow * inv);
}

extern "C" void kernel_launch(void* const* d_in, const int* in_sizes, int n_in,
                              void* d_out, int out_size, void* d_ws, size_t ws_size,
                              hipStream_t stream) {
  const float* x = (const float*)d_in[0];   // (8192, 256) fp32; pos (d_in[1]) is dead code
  float* kmT = (float*)d_ws;                // 256 KB
  float* out = (float*)d_out;

  kmeanT_kernel<<<256, 256, 0, stream>>>(x, kmT);
  fused_kernel<<<2048, 256, 0, stream>>>(x, kmT, out);
}